// Round 1
// baseline (324.104 us; speedup 1.0000x reference)
//
#include <hip/hip_runtime.h>

// FastMultiTaskGP: FFT(65536) of 136 upper-tri k1 rows + 16 y rows (ortho),
// per-frequency 16x16 Schur-complement inversion, logdet + quad reductions,
// write A.re / A.im (134 MB) + 2 scalars.
//
// FFT: 4x radix-16 Stockham passes (natural order). Ping-pong: d_out scratch
// <-> d_ws; final spectra in d_ws (76 MiB needed).
// Inversion: 16 lanes per frequency (lane = row of A), shuffle-based
// cross-row terms, lams staged in LDS.

#define TT 16
#define NF 65536
#define NPAIR 136
#define NROWS 152

static const size_t AIMAG  = 16777216;   // 16*16*65536
static const size_t OUT_LD = 33554432;
static const size_t OUT_QD = 33554433;

typedef float2 c32;

__device__ __forceinline__ c32 cmul(c32 a, c32 b) { return make_float2(a.x*b.x - a.y*b.y, a.x*b.y + a.y*b.x); }
__device__ __forceinline__ c32 cadd(c32 a, c32 b) { return make_float2(a.x + b.x, a.y + b.y); }
__device__ __forceinline__ c32 csub(c32 a, c32 b) { return make_float2(a.x - b.x, a.y - b.y); }

__constant__ c32 W16[16] = {
  { 1.0f, 0.0f}, { 0.92387953f,-0.38268343f}, { 0.70710678f,-0.70710678f}, { 0.38268343f,-0.92387953f},
  { 0.0f,-1.0f}, {-0.38268343f,-0.92387953f}, {-0.70710678f,-0.70710678f}, {-0.92387953f,-0.38268343f},
  {-1.0f, 0.0f}, {-0.92387953f, 0.38268343f}, {-0.70710678f, 0.70710678f}, {-0.38268343f, 0.92387953f},
  { 0.0f, 1.0f}, { 0.38268343f, 0.92387953f}, { 0.70710678f, 0.70710678f}, { 0.92387953f, 0.38268343f}
};

// forward DFT-4: X1 = s1 - i*s3, X3 = s1 + i*s3
__device__ __forceinline__ void dft4(c32 a0, c32 a1, c32 a2, c32 a3,
                                     c32& c0, c32& c1, c32& c2, c32& c3) {
  c32 s0 = cadd(a0, a2), s1 = csub(a0, a2);
  c32 s2 = cadd(a1, a3), s3 = csub(a1, a3);
  c0 = cadd(s0, s2);
  c2 = csub(s0, s2);
  c1 = make_float2(s1.x + s3.y, s1.y - s3.x);
  c3 = make_float2(s1.x - s3.y, s1.y + s3.x);
}

// 16-point forward DFT, natural order in/out (two radix-4 Stockham stages)
__device__ __forceinline__ void dft16(c32 v[16]) {
  c32 t[16];
  #pragma unroll
  for (int p = 0; p < 4; ++p) {
    c32 c0, c1, c2, c3;
    dft4(v[p], v[p+4], v[p+8], v[p+12], c0, c1, c2, c3);
    t[4*p+0] = c0;
    t[4*p+1] = cmul(c1, W16[p]);
    t[4*p+2] = cmul(c2, W16[(2*p) & 15]);
    t[4*p+3] = cmul(c3, W16[(3*p) & 15]);
  }
  #pragma unroll
  for (int q = 0; q < 4; ++q) {
    c32 c0, c1, c2, c3;
    dft4(t[q], t[q+4], t[q+8], t[q+12], c0, c1, c2, c3);
    v[q+0]  = c0;
    v[q+4]  = c1;
    v[q+8]  = c2;
    v[q+12] = c3;
  }
}

// Pass 1: real input, row mapping (136 packed upper-tri rows of k1, then 16 y
// rows scaled by 1/sqrt(N)). Stockham n=65536, s=1: read x[p + 4096 i],
// write y[16 p + j] with twiddle W_65536^{p j}.
__global__ __launch_bounds__(256) void fft_pass1(const float* __restrict__ k1,
                                                 const float* __restrict__ y,
                                                 c32* __restrict__ out) {
  const int row = blockIdx.y;
  const float* src;
  float scale = 1.0f;
  if (row < NPAIR) {
    int i = 0, rem = row;
    while (rem >= TT - i) { rem -= TT - i; ++i; }
    int j = i + rem;
    src = k1 + (size_t)(i * TT + j) * NF;
  } else {
    src = y + (size_t)(row - NPAIR) * NF;
    scale = 1.0f / 256.0f;   // ortho norm, sqrt(65536)=256
  }
  const int p = blockIdx.x * 256 + threadIdx.x;   // [0,4096)
  c32 v[16];
  #pragma unroll
  for (int i = 0; i < 16; ++i) v[i] = make_float2(src[p + 4096*i] * scale, 0.0f);
  dft16(v);
  float sa, ca;
  __sincosf(-6.2831853071795865f * (float)p / 65536.0f, &sa, &ca);
  c32 w1 = make_float2(ca, sa);
  c32 wj = w1;
  c32* dst = out + (size_t)row * NF + 16 * p;
  dst[0] = v[0];
  #pragma unroll
  for (int j = 1; j < 16; ++j) { dst[j] = cmul(v[j], wj); wj = cmul(wj, w1); }
}

// Generic Stockham radix-16 pass: current length NN, stride S.
// read in[w + 4096 i]; DFT16; twiddle W_NN^{p j}; write out[q + S*(16p + j)].
template<int NN, int S>
__global__ __launch_bounds__(256) void fft_pass(const c32* __restrict__ in,
                                                c32* __restrict__ out) {
  const int w = blockIdx.x * 256 + threadIdx.x;   // [0,4096)
  const int q = w & (S - 1);
  const int p = w / S;
  const size_t rbase = (size_t)blockIdx.y * NF;
  c32 v[16];
  #pragma unroll
  for (int i = 0; i < 16; ++i) v[i] = in[rbase + w + 4096*i];
  dft16(v);
  if constexpr (NN > 16) {
    float sa, ca;
    __sincosf(-6.2831853071795865f * (float)p / (float)NN, &sa, &ca);
    c32 w1 = make_float2(ca, sa);
    c32 wj = w1;
    #pragma unroll
    for (int j = 1; j < 16; ++j) { v[j] = cmul(v[j], wj); wj = cmul(wj, w1); }
  }
  c32* dst = out + rbase + q + (size_t)S * 16 * p;
  #pragma unroll
  for (int j = 0; j < 16; ++j) dst[(size_t)S * j] = v[j];
}

__global__ void init_out(float* __restrict__ out) {
  if (threadIdx.x == 0 && blockIdx.x == 0) {
    out[OUT_LD] = 0.0f;
    out[OUT_QD] = 0.0f;
  }
}

// Per-frequency 16x16 Schur-complement inversion.
// Block = 256 threads = 16 frequencies x 16 lanes (lane = row r of A).
// A row held in registers (compile-time-indexed only). Cross-row terms via
// width-16 shuffles. lams/yt staged in LDS (padded strides: conflict-free).
__global__ __launch_bounds__(256) void invert_write(const c32* __restrict__ spec,
                                                    float* __restrict__ out) {
  __shared__ c32 lam[16][NPAIR + 1];   // [freq][packed row], stride 137*2 words
  __shared__ c32 yts[16][17];          // [freq][task], padded
  __shared__ float redl[4], redq[4];

  const int t  = threadIdx.x;
  const int fi = t >> 4;
  const int r  = t & 15;
  const int f0 = blockIdx.x << 4;

  for (int idx = t; idx < NROWS * 16; idx += 256) {
    int row = idx >> 4, ff = idx & 15;
    c32 val = spec[(size_t)row * NF + f0 + ff];
    if (row < NPAIR) lam[ff][row] = val;
    else             yts[ff][row - NPAIR] = val;
  }
  __syncthreads();

  float Ar[16], Ai[16];
  #pragma unroll
  for (int k = 0; k < 16; ++k) { Ar[k] = 0.0f; Ai[k] = 0.0f; }

  c32 l00 = lam[fi][0];                 // pidx(0,0) = 0
  float ld = 0.0f;
  {
    float m00 = l00.x*l00.x + l00.y*l00.y;
    if (r == 0) {
      Ar[0] =  l00.x / m00;
      Ai[0] = -l00.y / m00;
      ld = 0.5f * __logf(m00);
    }
  }

  for (int l = 1; l < TT; ++l) {
    // Tm[r] = sum_{k<l} A[r][k] * B[k],  B[k] = lam[pidx(k,l)]
    float tr = 0.0f, ti = 0.0f;
    #pragma unroll
    for (int k = 0; k < 16; ++k) {
      if (k < l) {
        c32 B = lam[fi][(k * (31 - k)) / 2 + l];
        tr += Ar[k]*B.x - Ai[k]*B.y;
        ti += Ar[k]*B.y + Ai[k]*B.x;
      }
    }
    // M = sum_{i<l} conj(B[i]) * Tm[i]  (lanes r>=l have tr=ti=0)
    c32 Br = lam[fi][(r * (31 - r)) / 2 + l];
    float mr = Br.x*tr + Br.y*ti;
    float mi = Br.x*ti - Br.y*tr;
    #pragma unroll
    for (int d = 1; d < 16; d <<= 1) {
      mr += __shfl_xor(mr, d, 16);
      mi += __shfl_xor(mi, d, 16);
    }
    c32 ll = lam[fi][(l * (31 - l)) / 2 + l];
    float Sr = ll.x - mr, Si = ll.y - mi;
    float s2 = Sr*Sr + Si*Si;
    if (r == 0) ld += 0.5f * __logf(s2);
    float vr =  Sr / s2;                 // Sinv
    float vi = -Si / s2;
    float pr = tr*vr - ti*vi;            // P[r] = Tm[r] * Sinv
    float pi = tr*vi + ti*vr;

    #pragma unroll
    for (int j = 0; j < 16; ++j) {
      float tjr = __shfl(tr, j, 16);     // Tm[j] broadcast (all lanes execute)
      float tji = __shfl(ti, j, 16);
      if (j < l) {
        if (r < l) {
          // C[r][j] = A[r][j] + P[r] * conj(Tm[j])
          Ar[j] += pr*tjr + pi*tji;
          Ai[j] += pi*tjr - pr*tji;
        } else if (r == l) {
          // A[l][j] = -conj(P[j]) = -conj(Tm[j] * Sinv)
          float pjr = tjr*vr - tji*vi;
          float pji = tjr*vi + tji*vr;
          Ar[j] = -pjr;
          Ai[j] =  pji;
        }
      } else if (j == l) {
        if (r < l)       { Ar[j] = -pr;  Ai[j] = -pi; }   // column l: -P[r]
        else if (r == l) { Ar[j] =  vr;  Ai[j] =  vi; }   // diag: Sinv
      }
    }
  }

  // quad contribution: Re( conj(yt[r]) * sum_j A[r][j] yt[j] )
  float sr = 0.0f, si = 0.0f;
  #pragma unroll
  for (int j = 0; j < 16; ++j) {
    c32 yj = yts[fi][j];
    sr += Ar[j]*yj.x - Ai[j]*yj.y;
    si += Ar[j]*yj.y + Ai[j]*yj.x;
  }
  c32 yr = yts[fi][r];
  float qd = yr.x*sr + yr.y*si;

  // block reduction of ld (lane r==0 only holds data) and qd, then atomics
  #pragma unroll
  for (int d = 1; d < 64; d <<= 1) {
    ld += __shfl_xor(ld, d, 64);
    qd += __shfl_xor(qd, d, 64);
  }
  if ((t & 63) == 0) { redl[t >> 6] = ld; redq[t >> 6] = qd; }
  __syncthreads();
  if (t == 0) {
    atomicAdd(out + OUT_LD, redl[0] + redl[1] + redl[2] + redl[3]);
    atomicAdd(out + OUT_QD, redq[0] + redq[1] + redq[2] + redq[3]);
  }

  // store A: out[(r*16+j)*N + f] (real), +AIMAG (imag)
  const size_t f = (size_t)f0 + fi;
  #pragma unroll
  for (int j = 0; j < 16; ++j) {
    size_t o = (size_t)(r * 16 + j) * NF + f;
    out[o] = Ar[j];
    out[AIMAG + o] = Ai[j];
  }
}

extern "C" void kernel_launch(void* const* d_in, const int* in_sizes, int n_in,
                              void* d_out, int out_size, void* d_ws, size_t ws_size,
                              hipStream_t stream) {
  const float* k1 = (const float*)d_in[0];
  const float* y  = (const float*)d_in[1];
  float* out = (float*)d_out;
  c32* scratch = (c32*)d_out;   // 152*65536 c32 = 19.9M floats < 33.5M, overwritten later
  c32* spec    = (c32*)d_ws;    // needs 152*65536*8 B = 76 MiB of workspace

  dim3 grid(16, NROWS);
  dim3 blk(256);

  // Stockham passes: (n=65536,s=1) -> (4096,16) -> (256,256) -> (16,4096)
  fft_pass1        <<<grid, blk, 0, stream>>>(k1, y, scratch); // in  -> out-scratch
  fft_pass<4096,16><<<grid, blk, 0, stream>>>(scratch, spec);  // out -> ws
  fft_pass<256,256><<<grid, blk, 0, stream>>>(spec, scratch);  // ws  -> out
  fft_pass<16,4096><<<grid, blk, 0, stream>>>(scratch, spec);  // out -> ws (final spectra)

  init_out<<<1, 64, 0, stream>>>(out);
  invert_write<<<4096, blk, 0, stream>>>(spec, out);
}

// Round 2
// 309.293 us; speedup vs baseline: 1.0479x; 1.0479x over previous
//
#include <hip/hip_runtime.h>

// FastMultiTaskGP: FFT(65536) of 136 upper-tri k1 rows + 16 y rows (ortho),
// per-frequency 16x16 Schur-complement inversion, logdet + quad reductions,
// write A.re / A.im (134 MB) + 2 scalars.
//
// FFT: 4x radix-16 Stockham passes (natural order). Ping-pong: d_out scratch
// <-> d_ws; final spectra in d_ws (76 MiB needed).
// Inversion: 16 lanes per frequency (lane = row of A). l-loop FULLY UNROLLED
// (compile-time triangular bounds); cross-lane Tm broadcast via per-group LDS
// (wave-synchronous, no shuffles, no barriers); M computed per-lane.

#define TT 16
#define NF 65536
#define NPAIR 136
#define NROWS 152

static const size_t AIMAG  = 16777216;   // 16*16*65536
static const size_t OUT_LD = 33554432;
static const size_t OUT_QD = 33554433;

typedef float2 c32;

__device__ __forceinline__ c32 cmul(c32 a, c32 b) { return make_float2(a.x*b.x - a.y*b.y, a.x*b.y + a.y*b.x); }
__device__ __forceinline__ c32 cadd(c32 a, c32 b) { return make_float2(a.x + b.x, a.y + b.y); }
__device__ __forceinline__ c32 csub(c32 a, c32 b) { return make_float2(a.x - b.x, a.y - b.y); }

__constant__ c32 W16[16] = {
  { 1.0f, 0.0f}, { 0.92387953f,-0.38268343f}, { 0.70710678f,-0.70710678f}, { 0.38268343f,-0.92387953f},
  { 0.0f,-1.0f}, {-0.38268343f,-0.92387953f}, {-0.70710678f,-0.70710678f}, {-0.92387953f,-0.38268343f},
  {-1.0f, 0.0f}, {-0.92387953f, 0.38268343f}, {-0.70710678f, 0.70710678f}, {-0.38268343f, 0.92387953f},
  { 0.0f, 1.0f}, { 0.38268343f, 0.92387953f}, { 0.70710678f, 0.70710678f}, { 0.92387953f, 0.38268343f}
};

// forward DFT-4: X1 = s1 - i*s3, X3 = s1 + i*s3
__device__ __forceinline__ void dft4(c32 a0, c32 a1, c32 a2, c32 a3,
                                     c32& c0, c32& c1, c32& c2, c32& c3) {
  c32 s0 = cadd(a0, a2), s1 = csub(a0, a2);
  c32 s2 = cadd(a1, a3), s3 = csub(a1, a3);
  c0 = cadd(s0, s2);
  c2 = csub(s0, s2);
  c1 = make_float2(s1.x + s3.y, s1.y - s3.x);
  c3 = make_float2(s1.x - s3.y, s1.y + s3.x);
}

// 16-point forward DFT, natural order in/out (two radix-4 Stockham stages)
__device__ __forceinline__ void dft16(c32 v[16]) {
  c32 t[16];
  #pragma unroll
  for (int p = 0; p < 4; ++p) {
    c32 c0, c1, c2, c3;
    dft4(v[p], v[p+4], v[p+8], v[p+12], c0, c1, c2, c3);
    t[4*p+0] = c0;
    t[4*p+1] = cmul(c1, W16[p]);
    t[4*p+2] = cmul(c2, W16[(2*p) & 15]);
    t[4*p+3] = cmul(c3, W16[(3*p) & 15]);
  }
  #pragma unroll
  for (int q = 0; q < 4; ++q) {
    c32 c0, c1, c2, c3;
    dft4(t[q], t[q+4], t[q+8], t[q+12], c0, c1, c2, c3);
    v[q+0]  = c0;
    v[q+4]  = c1;
    v[q+8]  = c2;
    v[q+12] = c3;
  }
}

// Pass 1: real input, row mapping (136 packed upper-tri rows of k1, then 16 y
// rows scaled by 1/sqrt(N)). Stockham n=65536, s=1: read x[p + 4096 i],
// write y[16 p + j] with twiddle W_65536^{p j}.
__global__ __launch_bounds__(256) void fft_pass1(const float* __restrict__ k1,
                                                 const float* __restrict__ y,
                                                 c32* __restrict__ out) {
  const int row = blockIdx.y;
  const float* src;
  float scale = 1.0f;
  if (row < NPAIR) {
    int i = 0, rem = row;
    while (rem >= TT - i) { rem -= TT - i; ++i; }
    int j = i + rem;
    src = k1 + (size_t)(i * TT + j) * NF;
  } else {
    src = y + (size_t)(row - NPAIR) * NF;
    scale = 1.0f / 256.0f;   // ortho norm, sqrt(65536)=256
  }
  const int p = blockIdx.x * 256 + threadIdx.x;   // [0,4096)
  c32 v[16];
  #pragma unroll
  for (int i = 0; i < 16; ++i) v[i] = make_float2(src[p + 4096*i] * scale, 0.0f);
  dft16(v);
  float sa, ca;
  __sincosf(-6.2831853071795865f * (float)p / 65536.0f, &sa, &ca);
  c32 w1 = make_float2(ca, sa);
  c32 wj = w1;
  c32* dst = out + (size_t)row * NF + 16 * p;
  dst[0] = v[0];
  #pragma unroll
  for (int j = 1; j < 16; ++j) { dst[j] = cmul(v[j], wj); wj = cmul(wj, w1); }
}

// Generic Stockham radix-16 pass: current length NN, stride S.
// read in[w + 4096 i]; DFT16; twiddle W_NN^{p j}; write out[q + S*(16p + j)].
template<int NN, int S>
__global__ __launch_bounds__(256) void fft_pass(const c32* __restrict__ in,
                                                c32* __restrict__ out) {
  const int w = blockIdx.x * 256 + threadIdx.x;   // [0,4096)
  const int q = w & (S - 1);
  const int p = w / S;
  const size_t rbase = (size_t)blockIdx.y * NF;
  c32 v[16];
  #pragma unroll
  for (int i = 0; i < 16; ++i) v[i] = in[rbase + w + 4096*i];
  dft16(v);
  if constexpr (NN > 16) {
    float sa, ca;
    __sincosf(-6.2831853071795865f * (float)p / (float)NN, &sa, &ca);
    c32 w1 = make_float2(ca, sa);
    c32 wj = w1;
    #pragma unroll
    for (int j = 1; j < 16; ++j) { v[j] = cmul(v[j], wj); wj = cmul(wj, w1); }
  }
  c32* dst = out + rbase + q + (size_t)S * 16 * p;
  #pragma unroll
  for (int j = 0; j < 16; ++j) dst[(size_t)S * j] = v[j];
}

__global__ void init_out(float* __restrict__ out) {
  if (threadIdx.x == 0 && blockIdx.x == 0) {
    out[OUT_LD] = 0.0f;
    out[OUT_QD] = 0.0f;
  }
}

// Per-frequency 16x16 Schur-complement inversion.
// Block = 256 threads = 16 frequencies x 16 lanes (lane = row r of A).
// A row held in registers (compile-time-indexed only; l-loop fully unrolled).
// Cross-lane Tm broadcast via per-group LDS buffer (groups are within a wave,
// DS ops are in-order per wave -> no barrier). M computed per-lane (no
// shuffle-tree). lams staged in LDS (padded strides: conflict-free).
__global__ __launch_bounds__(256) void invert_write(const c32* __restrict__ spec,
                                                    float* __restrict__ out) {
  __shared__ c32 lam[16][NPAIR + 1];   // [freq][packed row], stride 137*8B
  __shared__ c32 yts[16][17];          // [freq][task], padded
  __shared__ c32 tmb[16][17];          // [freq][lane] Tm exchange, padded
  __shared__ float redl[4], redq[4];

  const int t  = threadIdx.x;
  const int fi = t >> 4;
  const int r  = t & 15;
  const int f0 = blockIdx.x << 4;

  for (int idx = t; idx < NROWS * 16; idx += 256) {
    int row = idx >> 4, ff = idx & 15;
    c32 val = spec[(size_t)row * NF + f0 + ff];
    if (row < NPAIR) lam[ff][row] = val;
    else             yts[ff][row - NPAIR] = val;
  }
  __syncthreads();

  float Ar[16], Ai[16];
  #pragma unroll
  for (int k = 0; k < 16; ++k) { Ar[k] = 0.0f; Ai[k] = 0.0f; }

  c32 l00 = lam[fi][0];                 // pidx(0,0) = 0
  float ld = 0.0f;
  {
    float m00 = l00.x*l00.x + l00.y*l00.y;
    if (r == 0) {
      Ar[0] =  l00.x / m00;
      Ai[0] = -l00.y / m00;
      ld = 0.5f * __logf(m00);
    }
  }

  #pragma unroll
  for (int l = 1; l < TT; ++l) {
    // Tm[r] = sum_{k<l} A[r][k] * B[k],  B[k] = lam[pidx(k,l)]
    // (lanes r >= l have zero A rows -> Tm = 0, harmless)
    float tr = 0.0f, ti = 0.0f;
    #pragma unroll
    for (int k = 0; k < l; ++k) {
      c32 B = lam[fi][(k * (31 - k)) / 2 + l];
      tr += Ar[k]*B.x - Ai[k]*B.y;
      ti += Ar[k]*B.y + Ai[k]*B.x;
    }
    // publish Tm to the group's exchange buffer (same wave: in-order DS)
    tmb[fi][r] = make_float2(tr, ti);

    // read back Tm[j] (j<l) and accumulate M = sum_j conj(B[j]) * Tm[j]
    float tmr[TT], tmi[TT];
    float mr = 0.0f, mi = 0.0f;
    #pragma unroll
    for (int j = 0; j < l; ++j) {
      c32 T = tmb[fi][j];
      c32 B = lam[fi][(j * (31 - j)) / 2 + l];
      tmr[j] = T.x; tmi[j] = T.y;
      mr += B.x*T.x + B.y*T.y;
      mi += B.x*T.y - B.y*T.x;
    }

    c32 ll = lam[fi][(l * (31 - l)) / 2 + l];
    float Sr = ll.x - mr, Si = ll.y - mi;
    float s2 = Sr*Sr + Si*Si;
    if (r == 0) ld += 0.5f * __logf(s2);
    float vr =  Sr / s2;                 // Sinv
    float vi = -Si / s2;
    float pr = tr*vr - ti*vi;            // P[r] = Tm[r] * Sinv
    float pi = tr*vi + ti*vr;

    #pragma unroll
    for (int j = 0; j < l; ++j) {
      if (r < l) {
        // C[r][j] = A[r][j] + P[r] * conj(Tm[j])
        Ar[j] += pr*tmr[j] + pi*tmi[j];
        Ai[j] += pi*tmr[j] - pr*tmi[j];
      } else if (r == l) {
        // A[l][j] = -conj(Tm[j] * Sinv)
        float pjr = tmr[j]*vr - tmi[j]*vi;
        float pji = tmr[j]*vi + tmi[j]*vr;
        Ar[j] = -pjr;
        Ai[j] =  pji;
      }
    }
    if (r < l)       { Ar[l] = -pr;  Ai[l] = -pi; }   // column l: -P[r]
    else if (r == l) { Ar[l] =  vr;  Ai[l] =  vi; }   // diag: Sinv
  }

  // quad contribution: Re( conj(yt[r]) * sum_j A[r][j] yt[j] )
  float sr = 0.0f, si = 0.0f;
  #pragma unroll
  for (int j = 0; j < 16; ++j) {
    c32 yj = yts[fi][j];
    sr += Ar[j]*yj.x - Ai[j]*yj.y;
    si += Ar[j]*yj.y + Ai[j]*yj.x;
  }
  c32 yr = yts[fi][r];
  float qd = yr.x*sr + yr.y*si;

  // block reduction of ld (lane r==0 only holds data) and qd, then atomics
  #pragma unroll
  for (int d = 1; d < 64; d <<= 1) {
    ld += __shfl_xor(ld, d, 64);
    qd += __shfl_xor(qd, d, 64);
  }
  if ((t & 63) == 0) { redl[t >> 6] = ld; redq[t >> 6] = qd; }
  __syncthreads();
  if (t == 0) {
    atomicAdd(out + OUT_LD, redl[0] + redl[1] + redl[2] + redl[3]);
    atomicAdd(out + OUT_QD, redq[0] + redq[1] + redq[2] + redq[3]);
  }

  // store A: out[(r*16+j)*N + f] (real), +AIMAG (imag)
  const size_t f = (size_t)f0 + fi;
  #pragma unroll
  for (int j = 0; j < 16; ++j) {
    size_t o = (size_t)(r * 16 + j) * NF + f;
    out[o] = Ar[j];
    out[AIMAG + o] = Ai[j];
  }
}

extern "C" void kernel_launch(void* const* d_in, const int* in_sizes, int n_in,
                              void* d_out, int out_size, void* d_ws, size_t ws_size,
                              hipStream_t stream) {
  const float* k1 = (const float*)d_in[0];
  const float* y  = (const float*)d_in[1];
  float* out = (float*)d_out;
  c32* scratch = (c32*)d_out;   // 152*65536 c32 = 19.9M floats < 33.5M, overwritten later
  c32* spec    = (c32*)d_ws;    // needs 152*65536*8 B = 76 MiB of workspace

  dim3 grid(16, NROWS);
  dim3 blk(256);

  // Stockham passes: (n=65536,s=1) -> (4096,16) -> (256,256) -> (16,4096)
  fft_pass1        <<<grid, blk, 0, stream>>>(k1, y, scratch); // in  -> out-scratch
  fft_pass<4096,16><<<grid, blk, 0, stream>>>(scratch, spec);  // out -> ws
  fft_pass<256,256><<<grid, blk, 0, stream>>>(spec, scratch);  // ws  -> out
  fft_pass<16,4096><<<grid, blk, 0, stream>>>(scratch, spec);  // out -> ws (final spectra)

  init_out<<<1, 64, 0, stream>>>(out);
  invert_write<<<4096, blk, 0, stream>>>(spec, out);
}

// Round 3
// 220.916 us; speedup vs baseline: 1.4671x; 1.4001x over previous
//
#include <hip/hip_runtime.h>

// FastMultiTaskGP: FFT(65536) of 136 upper-tri k1 rows + 16 y rows (ortho),
// per-frequency 16x16 Schur-complement inversion, logdet + quad reductions,
// write A.re / A.im (134 MB) + 2 scalars.
//
// Conjugate symmetry: inputs real => lam(N-f)=conj(lam(f)) => A(N-f)=conj(A(f)).
// Invert only f=0..32768 (2049 blocks), mirror-write the other half, weight
// the logdet/quad contributions by 2 for 0<f<32768.

#define TT 16
#define NF 65536
#define NPAIR 136
#define NROWS 152
#define NHALF 32768

static const size_t AIMAG  = 16777216;   // 16*16*65536
static const size_t OUT_LD = 33554432;
static const size_t OUT_QD = 33554433;

typedef float2 c32;

__device__ __forceinline__ c32 cmul(c32 a, c32 b) { return make_float2(a.x*b.x - a.y*b.y, a.x*b.y + a.y*b.x); }
__device__ __forceinline__ c32 cadd(c32 a, c32 b) { return make_float2(a.x + b.x, a.y + b.y); }
__device__ __forceinline__ c32 csub(c32 a, c32 b) { return make_float2(a.x - b.x, a.y - b.y); }

__constant__ c32 W16[16] = {
  { 1.0f, 0.0f}, { 0.92387953f,-0.38268343f}, { 0.70710678f,-0.70710678f}, { 0.38268343f,-0.92387953f},
  { 0.0f,-1.0f}, {-0.38268343f,-0.92387953f}, {-0.70710678f,-0.70710678f}, {-0.92387953f,-0.38268343f},
  {-1.0f, 0.0f}, {-0.92387953f, 0.38268343f}, {-0.70710678f, 0.70710678f}, {-0.38268343f, 0.92387953f},
  { 0.0f, 1.0f}, { 0.38268343f, 0.92387953f}, { 0.70710678f, 0.70710678f}, { 0.92387953f, 0.38268343f}
};

__device__ __forceinline__ void dft4(c32 a0, c32 a1, c32 a2, c32 a3,
                                     c32& c0, c32& c1, c32& c2, c32& c3) {
  c32 s0 = cadd(a0, a2), s1 = csub(a0, a2);
  c32 s2 = cadd(a1, a3), s3 = csub(a1, a3);
  c0 = cadd(s0, s2);
  c2 = csub(s0, s2);
  c1 = make_float2(s1.x + s3.y, s1.y - s3.x);
  c3 = make_float2(s1.x - s3.y, s1.y + s3.x);
}

__device__ __forceinline__ void dft16(c32 v[16]) {
  c32 t[16];
  #pragma unroll
  for (int p = 0; p < 4; ++p) {
    c32 c0, c1, c2, c3;
    dft4(v[p], v[p+4], v[p+8], v[p+12], c0, c1, c2, c3);
    t[4*p+0] = c0;
    t[4*p+1] = cmul(c1, W16[p]);
    t[4*p+2] = cmul(c2, W16[(2*p) & 15]);
    t[4*p+3] = cmul(c3, W16[(3*p) & 15]);
  }
  #pragma unroll
  for (int q = 0; q < 4; ++q) {
    c32 c0, c1, c2, c3;
    dft4(t[q], t[q+4], t[q+8], t[q+12], c0, c1, c2, c3);
    v[q+0]  = c0;
    v[q+4]  = c1;
    v[q+8]  = c2;
    v[q+12] = c3;
  }
}

__global__ __launch_bounds__(256) void fft_pass1(const float* __restrict__ k1,
                                                 const float* __restrict__ y,
                                                 c32* __restrict__ out) {
  const int row = blockIdx.y;
  const float* src;
  float scale = 1.0f;
  if (row < NPAIR) {
    int i = 0, rem = row;
    while (rem >= TT - i) { rem -= TT - i; ++i; }
    int j = i + rem;
    src = k1 + (size_t)(i * TT + j) * NF;
  } else {
    src = y + (size_t)(row - NPAIR) * NF;
    scale = 1.0f / 256.0f;   // ortho norm
  }
  const int p = blockIdx.x * 256 + threadIdx.x;   // [0,4096)
  c32 v[16];
  #pragma unroll
  for (int i = 0; i < 16; ++i) v[i] = make_float2(src[p + 4096*i] * scale, 0.0f);
  dft16(v);
  float sa, ca;
  __sincosf(-6.2831853071795865f * (float)p / 65536.0f, &sa, &ca);
  c32 w1 = make_float2(ca, sa);
  c32 wj = w1;
  c32* dst = out + (size_t)row * NF + 16 * p;
  dst[0] = v[0];
  #pragma unroll
  for (int j = 1; j < 16; ++j) { dst[j] = cmul(v[j], wj); wj = cmul(wj, w1); }
}

// Stockham radix-16 pass: length NN, stride S. TRIM: last pass only needs
// outputs with f = q + S*(16p+j) <= 32783  (j <= 8 when S=4096, p=0).
template<int NN, int S, bool TRIM>
__global__ __launch_bounds__(256) void fft_pass(const c32* __restrict__ in,
                                                c32* __restrict__ out) {
  const int w = blockIdx.x * 256 + threadIdx.x;   // [0,4096)
  const int q = w & (S - 1);
  const int p = w / S;
  const size_t rbase = (size_t)blockIdx.y * NF;
  c32 v[16];
  #pragma unroll
  for (int i = 0; i < 16; ++i) v[i] = in[rbase + w + 4096*i];
  dft16(v);
  if constexpr (NN > 16) {
    float sa, ca;
    __sincosf(-6.2831853071795865f * (float)p / (float)NN, &sa, &ca);
    c32 w1 = make_float2(ca, sa);
    c32 wj = w1;
    #pragma unroll
    for (int j = 1; j < 16; ++j) { v[j] = cmul(v[j], wj); wj = cmul(wj, w1); }
  }
  c32* dst = out + rbase + q + (size_t)S * 16 * p;
  #pragma unroll
  for (int j = 0; j < 16; ++j) {
    if (!TRIM || j <= 8) dst[(size_t)S * j] = v[j];
  }
}

__global__ void init_out(float* __restrict__ out) {
  if (threadIdx.x == 0 && blockIdx.x == 0) {
    out[OUT_LD] = 0.0f;
    out[OUT_QD] = 0.0f;
  }
}

// 16 lanes per frequency (lane = row r). l-loop fully unrolled, branch-free
// uniform update. Per step: publish float4(Tm, conj(B_own)*Tm) to group LDS
// (same wave -> in-order DS, no barrier); M-sum = 2 adds per read.
__global__ __launch_bounds__(256) void invert_write(const c32* __restrict__ spec,
                                                    float* __restrict__ out) {
  __shared__ c32 lam[16][NPAIR + 1];   // [freq][packed row]
  __shared__ c32 yts[16][17];
  __shared__ float4 tmb[16][17];
  __shared__ float redl[4], redq[4];

  const int t  = threadIdx.x;
  const int fi = t >> 4;
  const int r  = t & 15;
  const int f0 = blockIdx.x << 4;
  const int f  = f0 + fi;

  for (int idx = t; idx < NROWS * 16; idx += 256) {
    int row = idx >> 4, ff = idx & 15;
    c32 val = spec[(size_t)row * NF + f0 + ff];
    if (row < NPAIR) lam[ff][row] = val;
    else             yts[ff][row - NPAIR] = val;
  }
  __syncthreads();

  const int rowoff = (r * (31 - r)) >> 1;   // pidx(r,l) = rowoff + l

  float Ar[16], Ai[16];
  #pragma unroll
  for (int k = 0; k < 16; ++k) { Ar[k] = 0.0f; Ai[k] = 0.0f; }

  c32 l00 = lam[fi][0];
  float m00 = l00.x*l00.x + l00.y*l00.y;
  float im00 = 1.0f / m00;
  float ld = 0.5f * __logf(m00);            // all lanes (uniform), masked at reduce
  bool r0 = (r == 0);
  Ar[0] = r0 ?  l00.x * im00 : 0.0f;
  Ai[0] = r0 ? -l00.y * im00 : 0.0f;

  #pragma unroll
  for (int l = 1; l < TT; ++l) {
    // Tm[r] = sum_{k<l} A[r][k] * B[k],  B[k] = lam[k][l] (group-uniform reads)
    float tr = 0.0f, ti = 0.0f;
    #pragma unroll
    for (int k = 0; k < l; ++k) {
      c32 B = lam[fi][((k * (31 - k)) >> 1) + l];
      tr += Ar[k]*B.x - Ai[k]*B.y;
      ti += Ar[k]*B.y + Ai[k]*B.x;
    }
    // conj(B_own)*Tm for the M-reduction (B_own garbage for r>l, but Tm=0)
    c32 Bo = lam[fi][rowoff + l];
    float cbr = Bo.x*tr + Bo.y*ti;
    float cbi = Bo.x*ti - Bo.y*tr;
    tmb[fi][r] = make_float4(tr, ti, cbr, cbi);

    float tjr[TT], tji[TT];
    float mr = 0.0f, mi = 0.0f;
    #pragma unroll
    for (int j = 0; j < l; ++j) {
      float4 q = tmb[fi][j];
      tjr[j] = q.x; tji[j] = q.y;
      mr += q.z;    mi += q.w;
    }

    c32 ll = lam[fi][((l * (31 - l)) >> 1) + l];
    float Sr = ll.x - mr, Si = ll.y - mi;
    float s2 = Sr*Sr + Si*Si;
    ld += 0.5f * __logf(s2);
    float is2 = 1.0f / s2;
    float vr =  Sr * is2;                    // Sinv
    float vi = -Si * is2;
    float pr = tr*vr - ti*vi;                // P[r] = Tm[r]*Sinv  (0 for r>l)
    float pi = tr*vi + ti*vr;

    bool diag = (r == l);
    float cr = diag ? -vr : pr;              // c = diag ? -conj(Sinv) : P
    float ci = diag ?  vi : pi;
    float m  = diag ? 0.0f : 1.0f;

    #pragma unroll
    for (int j = 0; j < l; ++j) {
      // A[j] = m*A[j] + c*conj(Tm[j])
      Ar[j] = m*Ar[j] + cr*tjr[j] + ci*tji[j];
      Ai[j] = m*Ai[j] + ci*tjr[j] - cr*tji[j];
    }
    Ar[l] = diag ? vr : -pr;
    Ai[l] = diag ? vi : -pi;
  }

  // weights: f=0 / f=32768 once; 0<f<32768 twice (mirror); f>32768 excluded
  float w = (f == 0 || f == NHALF) ? 1.0f : (f < NHALF ? 2.0f : 0.0f);

  // quad: Re( conj(yt[r]) * sum_j A[r][j] yt[j] )
  float sr = 0.0f, si = 0.0f;
  #pragma unroll
  for (int j = 0; j < 16; ++j) {
    c32 yj = yts[fi][j];
    sr += Ar[j]*yj.x - Ai[j]*yj.y;
    si += Ar[j]*yj.y + Ai[j]*yj.x;
  }
  c32 yr = yts[fi][r];
  float qd = (yr.x*sr + yr.y*si) * w;
  float lw = r0 ? ld * w : 0.0f;

  #pragma unroll
  for (int d = 1; d < 64; d <<= 1) {
    lw += __shfl_xor(lw, d, 64);
    qd += __shfl_xor(qd, d, 64);
  }
  if ((t & 63) == 0) { redl[t >> 6] = lw; redq[t >> 6] = qd; }
  __syncthreads();
  if (t == 0) {
    atomicAdd(out + OUT_LD, redl[0] + redl[1] + redl[2] + redl[3]);
    atomicAdd(out + OUT_QD, redq[0] + redq[1] + redq[2] + redq[3]);
  }

  // direct store (f<=32768) and mirror store A(N-f)=conj(A(f)) (0<f<32768)
  if (f <= NHALF) {
    const size_t fd = (size_t)f;
    #pragma unroll
    for (int j = 0; j < 16; ++j) {
      size_t o = (size_t)(r * 16 + j) * NF + fd;
      out[o] = Ar[j];
      out[AIMAG + o] = Ai[j];
    }
  }
  if (f > 0 && f < NHALF) {
    const size_t fm = (size_t)(NF - f);
    #pragma unroll
    for (int j = 0; j < 16; ++j) {
      size_t o = (size_t)(r * 16 + j) * NF + fm;
      out[o] = Ar[j];
      out[AIMAG + o] = -Ai[j];
    }
  }
}

extern "C" void kernel_launch(void* const* d_in, const int* in_sizes, int n_in,
                              void* d_out, int out_size, void* d_ws, size_t ws_size,
                              hipStream_t stream) {
  const float* k1 = (const float*)d_in[0];
  const float* y  = (const float*)d_in[1];
  float* out = (float*)d_out;
  c32* scratch = (c32*)d_out;   // 152*65536 c32 = 79.7MB < 134MB, overwritten later
  c32* spec    = (c32*)d_ws;    // 76 MiB workspace

  dim3 grid(16, NROWS);
  dim3 blk(256);

  fft_pass1                <<<grid, blk, 0, stream>>>(k1, y, scratch);
  fft_pass<4096, 16, false><<<grid, blk, 0, stream>>>(scratch, spec);
  fft_pass<256, 256, false><<<grid, blk, 0, stream>>>(spec, scratch);
  fft_pass<16, 4096, true> <<<grid, blk, 0, stream>>>(scratch, spec);

  init_out<<<1, 64, 0, stream>>>(out);
  invert_write<<<2049, blk, 0, stream>>>(spec, out);
}

// Round 4
// 197.979 us; speedup vs baseline: 1.6371x; 1.1159x over previous
//
#include <hip/hip_runtime.h>

// FastMultiTaskGP: FFT(65536) of 136 upper-tri k1 rows + 16 y rows (ortho),
// per-frequency 16x16 Schur-complement inversion, logdet + quad reductions,
// write A.re / A.im (134 MB) + 2 scalars.
//
// Conjugate symmetry: inputs real => A(N-f)=conj(A(f)); invert only
// f=0..32768, mirror-write the rest, weight logdet/quad by 2 for 0<f<32768.
// Stores staged through LDS so each 16-lane cluster writes one aligned 64B
// line (16 consecutive frequencies), instead of 16x16B scatter.

#define TT 16
#define NF 65536
#define NPAIR 136
#define NROWS 152
#define NHALF 32768

static const size_t AIMAG  = 16777216;   // 16*16*65536
static const size_t OUT_LD = 33554432;
static const size_t OUT_QD = 33554433;

typedef float2 c32;

__device__ __forceinline__ c32 cmul(c32 a, c32 b) { return make_float2(a.x*b.x - a.y*b.y, a.x*b.y + a.y*b.x); }
__device__ __forceinline__ c32 cadd(c32 a, c32 b) { return make_float2(a.x + b.x, a.y + b.y); }
__device__ __forceinline__ c32 csub(c32 a, c32 b) { return make_float2(a.x - b.x, a.y - b.y); }

__constant__ c32 W16[16] = {
  { 1.0f, 0.0f}, { 0.92387953f,-0.38268343f}, { 0.70710678f,-0.70710678f}, { 0.38268343f,-0.92387953f},
  { 0.0f,-1.0f}, {-0.38268343f,-0.92387953f}, {-0.70710678f,-0.70710678f}, {-0.92387953f,-0.38268343f},
  {-1.0f, 0.0f}, {-0.92387953f, 0.38268343f}, {-0.70710678f, 0.70710678f}, {-0.38268343f, 0.92387953f},
  { 0.0f, 1.0f}, { 0.38268343f, 0.92387953f}, { 0.70710678f, 0.70710678f}, { 0.92387953f, 0.38268343f}
};

__device__ __forceinline__ void dft4(c32 a0, c32 a1, c32 a2, c32 a3,
                                     c32& c0, c32& c1, c32& c2, c32& c3) {
  c32 s0 = cadd(a0, a2), s1 = csub(a0, a2);
  c32 s2 = cadd(a1, a3), s3 = csub(a1, a3);
  c0 = cadd(s0, s2);
  c2 = csub(s0, s2);
  c1 = make_float2(s1.x + s3.y, s1.y - s3.x);
  c3 = make_float2(s1.x - s3.y, s1.y + s3.x);
}

__device__ __forceinline__ void dft16(c32 v[16]) {
  c32 t[16];
  #pragma unroll
  for (int p = 0; p < 4; ++p) {
    c32 c0, c1, c2, c3;
    dft4(v[p], v[p+4], v[p+8], v[p+12], c0, c1, c2, c3);
    t[4*p+0] = c0;
    t[4*p+1] = cmul(c1, W16[p]);
    t[4*p+2] = cmul(c2, W16[(2*p) & 15]);
    t[4*p+3] = cmul(c3, W16[(3*p) & 15]);
  }
  #pragma unroll
  for (int q = 0; q < 4; ++q) {
    c32 c0, c1, c2, c3;
    dft4(t[q], t[q+4], t[q+8], t[q+12], c0, c1, c2, c3);
    v[q+0]  = c0;
    v[q+4]  = c1;
    v[q+8]  = c2;
    v[q+12] = c3;
  }
}

__global__ __launch_bounds__(256) void fft_pass1(const float* __restrict__ k1,
                                                 const float* __restrict__ y,
                                                 c32* __restrict__ out) {
  const int row = blockIdx.y;
  const float* src;
  float scale = 1.0f;
  if (row < NPAIR) {
    int i = 0, rem = row;
    while (rem >= TT - i) { rem -= TT - i; ++i; }
    int j = i + rem;
    src = k1 + (size_t)(i * TT + j) * NF;
  } else {
    src = y + (size_t)(row - NPAIR) * NF;
    scale = 1.0f / 256.0f;   // ortho norm
  }
  const int p = blockIdx.x * 256 + threadIdx.x;   // [0,4096)
  c32 v[16];
  #pragma unroll
  for (int i = 0; i < 16; ++i) v[i] = make_float2(src[p + 4096*i] * scale, 0.0f);
  dft16(v);
  float sa, ca;
  __sincosf(-6.2831853071795865f * (float)p / 65536.0f, &sa, &ca);
  c32 w1 = make_float2(ca, sa);
  c32 wj = w1;
  c32* dst = out + (size_t)row * NF + 16 * p;
  dst[0] = v[0];
  #pragma unroll
  for (int j = 1; j < 16; ++j) { dst[j] = cmul(v[j], wj); wj = cmul(wj, w1); }
}

// Stockham radix-16 pass: length NN, stride S. TRIM: last pass only stores
// j <= 8 (covers all f <= 32783 that invert reads).
template<int NN, int S, bool TRIM>
__global__ __launch_bounds__(256) void fft_pass(const c32* __restrict__ in,
                                                c32* __restrict__ out) {
  const int w = blockIdx.x * 256 + threadIdx.x;   // [0,4096)
  const int q = w & (S - 1);
  const int p = w / S;
  const size_t rbase = (size_t)blockIdx.y * NF;
  c32 v[16];
  #pragma unroll
  for (int i = 0; i < 16; ++i) v[i] = in[rbase + w + 4096*i];
  dft16(v);
  if constexpr (NN > 16) {
    float sa, ca;
    __sincosf(-6.2831853071795865f * (float)p / (float)NN, &sa, &ca);
    c32 w1 = make_float2(ca, sa);
    c32 wj = w1;
    #pragma unroll
    for (int j = 1; j < 16; ++j) { v[j] = cmul(v[j], wj); wj = cmul(wj, w1); }
  }
  c32* dst = out + rbase + q + (size_t)S * 16 * p;
  #pragma unroll
  for (int j = 0; j < 16; ++j) {
    if (!TRIM || j <= 8) dst[(size_t)S * j] = v[j];
  }
}

__global__ void init_out(float* __restrict__ out) {
  if (threadIdx.x == 0 && blockIdx.x == 0) {
    out[OUT_LD] = 0.0f;
    out[OUT_QD] = 0.0f;
  }
}

// 16 lanes per frequency (lane = row r). l-loop fully unrolled, branch-free
// uniform update, LDS Tm exchange (wave-synchronous). Store phase staged
// through LDS plane buffer for full-line coalesced global writes.
__global__ __launch_bounds__(256) void invert_write(const c32* __restrict__ spec,
                                                    float* __restrict__ out) {
  __shared__ union {
    struct {
      c32 lam[16][NPAIR + 1];   // [freq][packed row]
      c32 yts[16][17];
      float4 tmb[16][17];
    } rec;
    float plane[16][260];       // [freq][rr], rr stride 260: conflict-free reads
  } sh;
  __shared__ float redl[4], redq[4];

  const int t  = threadIdx.x;
  const int fi = t >> 4;
  const int r  = t & 15;
  const int f0 = blockIdx.x << 4;
  const int f  = f0 + fi;

  for (int idx = t; idx < NROWS * 16; idx += 256) {
    int row = idx >> 4, ff = idx & 15;
    c32 val = spec[(size_t)row * NF + f0 + ff];
    if (row < NPAIR) sh.rec.lam[ff][row] = val;
    else             sh.rec.yts[ff][row - NPAIR] = val;
  }
  __syncthreads();

  const int rowoff = (r * (31 - r)) >> 1;   // pidx(r,l) = rowoff + l

  float Ar[16], Ai[16];
  #pragma unroll
  for (int k = 0; k < 16; ++k) { Ar[k] = 0.0f; Ai[k] = 0.0f; }

  c32 l00 = sh.rec.lam[fi][0];
  float m00 = l00.x*l00.x + l00.y*l00.y;
  float im00 = 1.0f / m00;
  float ld = 0.5f * __logf(m00);            // uniform across lanes, masked at reduce
  bool r0 = (r == 0);
  Ar[0] = r0 ?  l00.x * im00 : 0.0f;
  Ai[0] = r0 ? -l00.y * im00 : 0.0f;

  #pragma unroll
  for (int l = 1; l < TT; ++l) {
    // Tm[r] = sum_{k<l} A[r][k] * B[k]
    float tr = 0.0f, ti = 0.0f;
    #pragma unroll
    for (int k = 0; k < l; ++k) {
      c32 B = sh.rec.lam[fi][((k * (31 - k)) >> 1) + l];
      tr += Ar[k]*B.x - Ai[k]*B.y;
      ti += Ar[k]*B.y + Ai[k]*B.x;
    }
    c32 Bo = sh.rec.lam[fi][rowoff + l];
    float cbr = Bo.x*tr + Bo.y*ti;
    float cbi = Bo.x*ti - Bo.y*tr;
    sh.rec.tmb[fi][r] = make_float4(tr, ti, cbr, cbi);   // same wave: in-order DS

    float tjr[TT], tji[TT];
    float mr = 0.0f, mi = 0.0f;
    #pragma unroll
    for (int j = 0; j < l; ++j) {
      float4 q = sh.rec.tmb[fi][j];
      tjr[j] = q.x; tji[j] = q.y;
      mr += q.z;    mi += q.w;
    }

    c32 ll = sh.rec.lam[fi][((l * (31 - l)) >> 1) + l];
    float Sr = ll.x - mr, Si = ll.y - mi;
    float s2 = Sr*Sr + Si*Si;
    ld += 0.5f * __logf(s2);
    float is2 = 1.0f / s2;
    float vr =  Sr * is2;                    // Sinv
    float vi = -Si * is2;
    float pr = tr*vr - ti*vi;                // P[r] (0 for r>l)
    float pi = tr*vi + ti*vr;

    bool diag = (r == l);
    float cr = diag ? -vr : pr;
    float ci = diag ?  vi : pi;
    float m  = diag ? 0.0f : 1.0f;

    #pragma unroll
    for (int j = 0; j < l; ++j) {
      Ar[j] = m*Ar[j] + cr*tjr[j] + ci*tji[j];
      Ai[j] = m*Ai[j] + ci*tjr[j] - cr*tji[j];
    }
    Ar[l] = diag ? vr : -pr;
    Ai[l] = diag ? vi : -pi;
  }

  // weights: f=0 / f=32768 once; 0<f<32768 twice; f>32768 excluded
  float w = (f == 0 || f == NHALF) ? 1.0f : (f < NHALF ? 2.0f : 0.0f);

  // quad: Re( conj(yt[r]) * sum_j A[r][j] yt[j] )
  float sr = 0.0f, si = 0.0f;
  #pragma unroll
  for (int j = 0; j < 16; ++j) {
    c32 yj = sh.rec.yts[fi][j];
    sr += Ar[j]*yj.x - Ai[j]*yj.y;
    si += Ar[j]*yj.y + Ai[j]*yj.x;
  }
  c32 yr = sh.rec.yts[fi][r];
  float qd = (yr.x*sr + yr.y*si) * w;
  float lw = r0 ? ld * w : 0.0f;

  #pragma unroll
  for (int d = 1; d < 64; d <<= 1) {
    lw += __shfl_xor(lw, d, 64);
    qd += __shfl_xor(qd, d, 64);
  }
  if ((t & 63) == 0) { redl[t >> 6] = lw; redq[t >> 6] = qd; }
  __syncthreads();   // also: all recursion LDS reads complete before staging
  if (t == 0) {
    atomicAdd(out + OUT_LD, redl[0] + redl[1] + redl[2] + redl[3]);
    atomicAdd(out + OUT_QD, redq[0] + redq[1] + redq[2] + redq[3]);
  }

  // ---- coalesced store via LDS staging ----
  const int lf = t & 15;            // frequency offset within block
  const int cl = t >> 4;            // row cluster
  const int fL = f0 + lf;
  const bool dir_ok = (fL <= NHALF);
  const bool mir_ok = (fL > 0 && fL < NHALF);
  const size_t fD = (size_t)fL;
  const size_t fM = (size_t)(NF - fL);

  // RE plane
  {
    float4* prow = (float4*)&sh.plane[fi][r * 16];   // 16B-aligned (row stride 1040B)
    prow[0] = make_float4(Ar[0],  Ar[1],  Ar[2],  Ar[3]);
    prow[1] = make_float4(Ar[4],  Ar[5],  Ar[6],  Ar[7]);
    prow[2] = make_float4(Ar[8],  Ar[9],  Ar[10], Ar[11]);
    prow[3] = make_float4(Ar[12], Ar[13], Ar[14], Ar[15]);
  }
  __syncthreads();
  #pragma unroll
  for (int u = 0; u < 16; ++u) {
    int rr = u * 16 + cl;
    float v = sh.plane[lf][rr];
    size_t o = (size_t)rr * NF;
    if (dir_ok) out[o + fD] = v;
    if (mir_ok) out[o + fM] = v;
  }
  __syncthreads();
  // IM plane
  {
    float4* prow = (float4*)&sh.plane[fi][r * 16];
    prow[0] = make_float4(Ai[0],  Ai[1],  Ai[2],  Ai[3]);
    prow[1] = make_float4(Ai[4],  Ai[5],  Ai[6],  Ai[7]);
    prow[2] = make_float4(Ai[8],  Ai[9],  Ai[10], Ai[11]);
    prow[3] = make_float4(Ai[12], Ai[13], Ai[14], Ai[15]);
  }
  __syncthreads();
  #pragma unroll
  for (int u = 0; u < 16; ++u) {
    int rr = u * 16 + cl;
    float v = sh.plane[lf][rr];
    size_t o = AIMAG + (size_t)rr * NF;
    if (dir_ok) out[o + fD] = v;
    if (mir_ok) out[o + fM] = -v;
  }
}

extern "C" void kernel_launch(void* const* d_in, const int* in_sizes, int n_in,
                              void* d_out, int out_size, void* d_ws, size_t ws_size,
                              hipStream_t stream) {
  const float* k1 = (const float*)d_in[0];
  const float* y  = (const float*)d_in[1];
  float* out = (float*)d_out;
  c32* scratch = (c32*)d_out;   // 79.7 MB < 134 MB out buffer, overwritten later
  c32* spec    = (c32*)d_ws;    // 76 MiB workspace

  dim3 grid(16, NROWS);
  dim3 blk(256);

  fft_pass1                <<<grid, blk, 0, stream>>>(k1, y, scratch);
  fft_pass<4096, 16, false><<<grid, blk, 0, stream>>>(scratch, spec);
  fft_pass<256, 256, false><<<grid, blk, 0, stream>>>(spec, scratch);
  fft_pass<16, 4096, true> <<<grid, blk, 0, stream>>>(scratch, spec);

  init_out<<<1, 64, 0, stream>>>(out);
  invert_write<<<2049, blk, 0, stream>>>(spec, out);
}

// Round 5
// 191.333 us; speedup vs baseline: 1.6939x; 1.0347x over previous
//
#include <hip/hip_runtime.h>

// FastMultiTaskGP: FFT(65536) of 136 upper-tri k1 rows + 16 y rows (ortho),
// per-frequency 16x16 Schur-complement inversion (Hermitian), logdet + quad,
// write A.re / A.im (134 MB) + 2 scalars.
//
// Conjugate symmetry: real inputs => A(N-f)=conj(A(f)); invert f=0..32768,
// mirror-write the rest, weight logdet/quad by 2 for 0<f<32768.
// Inversion layout: 4 lanes per frequency (lane owns rows 4g..4g+3),
// 64 freqs per 256-thread block. Cross-row Tm exchange via DPP quad_perm
// (pure VALU), M-reduce via DPP xor. lam in LDS transposed [entry][freq]
// (conflict-free broadcasts).

#define TT 16
#define NF 65536
#define NPAIR 136
#define NROWS 152
#define NHALF 32768

static const size_t AIMAG  = 16777216;   // 16*16*65536
static const size_t OUT_LD = 33554432;
static const size_t OUT_QD = 33554433;

typedef float2 c32;

__device__ __forceinline__ c32 cmul(c32 a, c32 b) { return make_float2(a.x*b.x - a.y*b.y, a.x*b.y + a.y*b.x); }
__device__ __forceinline__ c32 cadd(c32 a, c32 b) { return make_float2(a.x + b.x, a.y + b.y); }
__device__ __forceinline__ c32 csub(c32 a, c32 b) { return make_float2(a.x - b.x, a.y - b.y); }

// DPP helpers (ctrl must be a literal/ICE at each use site)
#define DPPF(x, ctrl) __int_as_float(__builtin_amdgcn_update_dpp( \
    __float_as_int(x), __float_as_int(x), (ctrl), 0xF, 0xF, false))
// quad xor1 = [1,0,3,2] = 0xB1 ; quad xor2 = [2,3,0,1] = 0x4E ; bcast q = 0x55*q

__constant__ c32 W16[16] = {
  { 1.0f, 0.0f}, { 0.92387953f,-0.38268343f}, { 0.70710678f,-0.70710678f}, { 0.38268343f,-0.92387953f},
  { 0.0f,-1.0f}, {-0.38268343f,-0.92387953f}, {-0.70710678f,-0.70710678f}, {-0.92387953f,-0.38268343f},
  {-1.0f, 0.0f}, {-0.92387953f, 0.38268343f}, {-0.70710678f, 0.70710678f}, {-0.38268343f, 0.92387953f},
  { 0.0f, 1.0f}, { 0.38268343f, 0.92387953f}, { 0.70710678f, 0.70710678f}, { 0.92387953f, 0.38268343f}
};

__device__ __forceinline__ void dft4(c32 a0, c32 a1, c32 a2, c32 a3,
                                     c32& c0, c32& c1, c32& c2, c32& c3) {
  c32 s0 = cadd(a0, a2), s1 = csub(a0, a2);
  c32 s2 = cadd(a1, a3), s3 = csub(a1, a3);
  c0 = cadd(s0, s2);
  c2 = csub(s0, s2);
  c1 = make_float2(s1.x + s3.y, s1.y - s3.x);
  c3 = make_float2(s1.x - s3.y, s1.y + s3.x);
}

__device__ __forceinline__ void dft16(c32 v[16]) {
  c32 t[16];
  #pragma unroll
  for (int p = 0; p < 4; ++p) {
    c32 c0, c1, c2, c3;
    dft4(v[p], v[p+4], v[p+8], v[p+12], c0, c1, c2, c3);
    t[4*p+0] = c0;
    t[4*p+1] = cmul(c1, W16[p]);
    t[4*p+2] = cmul(c2, W16[(2*p) & 15]);
    t[4*p+3] = cmul(c3, W16[(3*p) & 15]);
  }
  #pragma unroll
  for (int q = 0; q < 4; ++q) {
    c32 c0, c1, c2, c3;
    dft4(t[q], t[q+4], t[q+8], t[q+12], c0, c1, c2, c3);
    v[q+0]  = c0;
    v[q+4]  = c1;
    v[q+8]  = c2;
    v[q+12] = c3;
  }
}

__global__ __launch_bounds__(256) void fft_pass1(const float* __restrict__ k1,
                                                 const float* __restrict__ y,
                                                 c32* __restrict__ out) {
  const int row = blockIdx.y;
  const float* src;
  float scale = 1.0f;
  if (row < NPAIR) {
    int i = 0, rem = row;
    while (rem >= TT - i) { rem -= TT - i; ++i; }
    int j = i + rem;
    src = k1 + (size_t)(i * TT + j) * NF;
  } else {
    src = y + (size_t)(row - NPAIR) * NF;
    scale = 1.0f / 256.0f;   // ortho norm
  }
  const int p = blockIdx.x * 256 + threadIdx.x;   // [0,4096)
  c32 v[16];
  #pragma unroll
  for (int i = 0; i < 16; ++i) v[i] = make_float2(src[p + 4096*i] * scale, 0.0f);
  dft16(v);
  float sa, ca;
  __sincosf(-6.2831853071795865f * (float)p / 65536.0f, &sa, &ca);
  c32 w1 = make_float2(ca, sa);
  c32 wj = w1;
  c32* dst = out + (size_t)row * NF + 16 * p;
  dst[0] = v[0];
  #pragma unroll
  for (int j = 1; j < 16; ++j) { dst[j] = cmul(v[j], wj); wj = cmul(wj, w1); }
}

// Stockham radix-16 pass: length NN, stride S. TRIM: last pass stores j<=8
// (covers all f < 36864 that invert reads).
template<int NN, int S, bool TRIM>
__global__ __launch_bounds__(256) void fft_pass(const c32* __restrict__ in,
                                                c32* __restrict__ out) {
  const int w = blockIdx.x * 256 + threadIdx.x;   // [0,4096)
  const int q = w & (S - 1);
  const int p = w / S;
  const size_t rbase = (size_t)blockIdx.y * NF;
  c32 v[16];
  #pragma unroll
  for (int i = 0; i < 16; ++i) v[i] = in[rbase + w + 4096*i];
  dft16(v);
  if constexpr (NN > 16) {
    float sa, ca;
    __sincosf(-6.2831853071795865f * (float)p / (float)NN, &sa, &ca);
    c32 w1 = make_float2(ca, sa);
    c32 wj = w1;
    #pragma unroll
    for (int j = 1; j < 16; ++j) { v[j] = cmul(v[j], wj); wj = cmul(wj, w1); }
  }
  c32* dst = out + rbase + q + (size_t)S * 16 * p;
  #pragma unroll
  for (int j = 0; j < 16; ++j) {
    if (!TRIM || j <= 8) dst[(size_t)S * j] = v[j];
  }
}

__global__ void init_out(float* __restrict__ out) {
  if (threadIdx.x == 0 && blockIdx.x == 0) {
    out[OUT_LD] = 0.0f;
    out[OUT_QD] = 0.0f;
  }
}

// ---- Schur step L (compile-time), 4 lanes/freq, lane owns rows 4g..4g+3 ----
// lamf: &lam[0][fi], element stride 64 c32. Tm exchange via DPP.
#define UPDATE_J(J)                                                          \
  if constexpr ((J) < L) {                                                   \
    float tjr = DPPF(tr[(J)&3], 0x55*((J)>>2));                              \
    float tji = DPPF(ti[(J)&3], 0x55*((J)>>2));                              \
    _Pragma("unroll")                                                        \
    for (int m = 0; m < 4; ++m) {                                            \
      Ar[m][(J)] = mf[m]*Ar[m][(J)] + cr[m]*tjr + ci[m]*tji;                 \
      Ai[m][(J)] = mf[m]*Ai[m][(J)] + ci[m]*tjr - cr[m]*tji;                 \
    }                                                                        \
  }

template<int L>
__device__ __forceinline__ void schur_step(const c32* __restrict__ lamf,
                                           float (&Ar)[4][16], float (&Ai)[4][16],
                                           const int (&row)[4], const int (&ro)[4],
                                           float& ld) {
  float tr[4] = {0.f,0.f,0.f,0.f}, ti[4] = {0.f,0.f,0.f,0.f};
  #pragma unroll
  for (int k = 0; k < L; ++k) {
    c32 B = lamf[(((k*(31-k))>>1) + L) * 64];    // quad-broadcast read
    #pragma unroll
    for (int m = 0; m < 4; ++m) {
      tr[m] += Ar[m][k]*B.x - Ai[m][k]*B.y;
      ti[m] += Ar[m][k]*B.y + Ai[m][k]*B.x;
    }
  }
  // partial M over own rows (rows >= L have Tm = 0; garbage B harmless/finite)
  float mr = 0.f, mi = 0.f;
  #pragma unroll
  for (int m = 0; m < 4; ++m) {
    c32 Bo = lamf[(ro[m] + L) * 64];
    mr += Bo.x*tr[m] + Bo.y*ti[m];
    mi += Bo.x*ti[m] - Bo.y*tr[m];
  }
  // quad xor-reduce -> all 4 lanes hold full M
  mr += DPPF(mr, 0xB1); mi += DPPF(mi, 0xB1);
  mr += DPPF(mr, 0x4E); mi += DPPF(mi, 0x4E);

  c32 ll = lamf[(((L*(31-L))>>1) + L) * 64];
  float Sr = ll.x - mr, Si = ll.y - mi;
  float s2 = Sr*Sr + Si*Si;
  ld += 0.5f * __logf(s2);
  float is2 = 1.0f / s2;
  float vr = Sr * is2, vi = -Si * is2;         // Sinv

  float pr[4], pi[4], cr[4], ci[4], mf[4];
  #pragma unroll
  for (int m = 0; m < 4; ++m) {
    pr[m] = tr[m]*vr - ti[m]*vi;               // P (0 for rows > L)
    pi[m] = tr[m]*vi + ti[m]*vr;
    bool diag = (row[m] == L);
    cr[m] = diag ? -vr : pr[m];
    ci[m] = diag ?  vi : pi[m];
    mf[m] = diag ? 0.0f : 1.0f;
  }
  UPDATE_J(0)  UPDATE_J(1)  UPDATE_J(2)  UPDATE_J(3)
  UPDATE_J(4)  UPDATE_J(5)  UPDATE_J(6)  UPDATE_J(7)
  UPDATE_J(8)  UPDATE_J(9)  UPDATE_J(10) UPDATE_J(11)
  UPDATE_J(12) UPDATE_J(13) UPDATE_J(14) UPDATE_J(15)
  #pragma unroll
  for (int m = 0; m < 4; ++m) {
    bool diag = (row[m] == L);
    Ar[m][L] = diag ? vr : -pr[m];
    Ai[m][L] = diag ? vi : -pi[m];
  }
}

__global__ __launch_bounds__(256, 2) void invert_write(const c32* __restrict__ spec,
                                                       float* __restrict__ out) {
  __shared__ union {
    struct {
      c32 lam[NPAIR + 1][64];   // [packed entry][freq]
      c32 yts[TT][64];          // [task][freq]
    } rec;
    float plane[64][261];       // [freq][rr swizzled], stride 261: 2-way reads
  } sh;
  __shared__ float redl[4], redq[4];

  const int t  = threadIdx.x;
  const int fi = t >> 2;            // freq within block [0,64)
  const int g  = t & 3;             // quad lane = row group
  const int f0 = blockIdx.x << 6;
  const int f  = f0 + fi;

  for (int idx = t; idx < NROWS * 64; idx += 256) {
    int rowi = idx >> 6, ff = idx & 63;
    c32 val = spec[(size_t)rowi * NF + f0 + ff];
    if (rowi < NPAIR) sh.rec.lam[rowi][ff] = val;
    else              sh.rec.yts[rowi - NPAIR][ff] = val;
  }
  __syncthreads();

  int row[4], ro[4];
  #pragma unroll
  for (int m = 0; m < 4; ++m) {
    row[m] = 4*g + m;
    ro[m]  = (row[m] * (31 - row[m])) >> 1;
  }

  const c32* lamf = &sh.rec.lam[0][fi];
  const c32* ytf  = &sh.rec.yts[0][fi];

  float Ar[4][16], Ai[4][16];
  #pragma unroll
  for (int m = 0; m < 4; ++m)
    #pragma unroll
    for (int j = 0; j < 16; ++j) { Ar[m][j] = 0.0f; Ai[m][j] = 0.0f; }

  c32 l00 = lamf[0];
  float m00 = l00.x*l00.x + l00.y*l00.y;
  float im00 = 1.0f / m00;
  float ld = 0.5f * __logf(m00);
  if (row[0] == 0) {                 // only lane g==0 owns row 0
    Ar[0][0] =  l00.x * im00;
    Ai[0][0] = -l00.y * im00;
  }

  schur_step< 1>(lamf, Ar, Ai, row, ro, ld);
  schur_step< 2>(lamf, Ar, Ai, row, ro, ld);
  schur_step< 3>(lamf, Ar, Ai, row, ro, ld);
  schur_step< 4>(lamf, Ar, Ai, row, ro, ld);
  schur_step< 5>(lamf, Ar, Ai, row, ro, ld);
  schur_step< 6>(lamf, Ar, Ai, row, ro, ld);
  schur_step< 7>(lamf, Ar, Ai, row, ro, ld);
  schur_step< 8>(lamf, Ar, Ai, row, ro, ld);
  schur_step< 9>(lamf, Ar, Ai, row, ro, ld);
  schur_step<10>(lamf, Ar, Ai, row, ro, ld);
  schur_step<11>(lamf, Ar, Ai, row, ro, ld);
  schur_step<12>(lamf, Ar, Ai, row, ro, ld);
  schur_step<13>(lamf, Ar, Ai, row, ro, ld);
  schur_step<14>(lamf, Ar, Ai, row, ro, ld);
  schur_step<15>(lamf, Ar, Ai, row, ro, ld);

  // quad: qd partial over own rows, then quad-reduce
  float qd = 0.0f;
  #pragma unroll
  for (int m = 0; m < 4; ++m) {
    float sr = 0.f, si = 0.f;
    #pragma unroll
    for (int j = 0; j < 16; ++j) {
      c32 yj = ytf[j * 64];
      sr += Ar[m][j]*yj.x - Ai[m][j]*yj.y;
      si += Ar[m][j]*yj.y + Ai[m][j]*yj.x;
    }
    c32 yo = ytf[row[m] * 64];
    qd += yo.x*sr + yo.y*si;
  }
  qd += DPPF(qd, 0xB1);
  qd += DPPF(qd, 0x4E);

  float w  = (f == 0 || f == NHALF) ? 1.0f : (f < NHALF ? 2.0f : 0.0f);
  float lw = (g == 0) ? ld * w : 0.0f;
  float qw = (g == 0) ? qd * w : 0.0f;

  #pragma unroll
  for (int d = 1; d < 64; d <<= 1) {
    lw += __shfl_xor(lw, d, 64);
    qw += __shfl_xor(qw, d, 64);
  }
  if ((t & 63) == 0) { redl[t >> 6] = lw; redq[t >> 6] = qw; }
  __syncthreads();   // also: recursion LDS reads complete before plane reuse
  if (t == 0) {
    atomicAdd(out + OUT_LD, redl[0] + redl[1] + redl[2] + redl[3]);
    atomicAdd(out + OUT_QD, redq[0] + redq[1] + redq[2] + redq[3]);
  }

  // ---- coalesced store via LDS plane (64 consecutive f per wave instr) ----
  const int fl  = t & 63;
  const int wid = t >> 6;
  const int fg  = f0 + fl;
  const bool dok = (fg <= NHALF);
  const bool mok = (fg > 0 && fg < NHALF);
  const size_t fD = (size_t)fg;
  const size_t fM = (size_t)(NF - fg);

  // RE plane
  #pragma unroll
  for (int m = 0; m < 4; ++m)
    #pragma unroll
    for (int j = 0; j < 16; ++j) {
      int rr = row[m] * 16 + j;
      sh.plane[fi][rr ^ g] = Ar[m][j];    // g-XOR: conflict-free writes
    }
  __syncthreads();
  #pragma unroll 8
  for (int it = 0; it < 64; ++it) {
    int rr = wid + 4 * it;
    float v = sh.plane[fl][rr ^ ((rr >> 6) & 3)];
    size_t o = (size_t)rr * NF;
    if (dok) out[o + fD] = v;
    if (mok) out[o + fM] = v;
  }
  __syncthreads();
  // IM plane
  #pragma unroll
  for (int m = 0; m < 4; ++m)
    #pragma unroll
    for (int j = 0; j < 16; ++j) {
      int rr = row[m] * 16 + j;
      sh.plane[fi][rr ^ g] = Ai[m][j];
    }
  __syncthreads();
  #pragma unroll 8
  for (int it = 0; it < 64; ++it) {
    int rr = wid + 4 * it;
    float v = sh.plane[fl][rr ^ ((rr >> 6) & 3)];
    size_t o = AIMAG + (size_t)rr * NF;
    if (dok) out[o + fD] = v;
    if (mok) out[o + fM] = -v;
  }
}

extern "C" void kernel_launch(void* const* d_in, const int* in_sizes, int n_in,
                              void* d_out, int out_size, void* d_ws, size_t ws_size,
                              hipStream_t stream) {
  const float* k1 = (const float*)d_in[0];
  const float* y  = (const float*)d_in[1];
  float* out = (float*)d_out;
  c32* scratch = (c32*)d_out;   // 79.7 MB < 134 MB out buffer, overwritten later
  c32* spec    = (c32*)d_ws;    // 76 MiB workspace

  dim3 grid(16, NROWS);
  dim3 blk(256);

  fft_pass1                <<<grid, blk, 0, stream>>>(k1, y, scratch);
  fft_pass<4096, 16, false><<<grid, blk, 0, stream>>>(scratch, spec);
  fft_pass<256, 256, false><<<grid, blk, 0, stream>>>(spec, scratch);
  fft_pass<16, 4096, true> <<<grid, blk, 0, stream>>>(scratch, spec);

  init_out<<<1, 64, 0, stream>>>(out);
  invert_write<<<513, blk, 0, stream>>>(spec, out);   // f = 0..32768 (+tail)
}